// Round 8
// baseline (202.565 us; speedup 1.0000x reference)
//
#include <hip/hip_runtime.h>

#define NDATA 100000
#define KP1 16385            // NCE_K + 1
#define BSZ 64
#define PTOT (BSZ * KP1)     // 1,048,640
#define NCHUNK 6250          // NDATA / 16 (exact)
#define INV_T (1.0f / 0.07f)
#define GX 320               // sgemm blocks per bank (1280 waves/bank)

typedef short short8 __attribute__((ext_vector_type(8)));
typedef float f32x4 __attribute__((ext_vector_type(4)));

__device__ __forceinline__ float wave_reduce64(float v) {
    #pragma unroll
    for (int off = 32; off >= 1; off >>= 1) v += __shfl_xor(v, off);
    return v;
}

__device__ __forceinline__ unsigned short f2bf(float f) {
    unsigned u = __float_as_uint(f);
    u += 0x7FFFu + ((u >> 16) & 1u);   // round-to-nearest-even
    return (unsigned short)(u >> 16);
}

__device__ __forceinline__ float bf2f(unsigned short u) {
    return __uint_as_float((unsigned)u << 16);
}

__device__ __forceinline__ float dot4(float4 a, float4 b, float acc) {
    acc = fmaf(a.x, b.x, acc);
    acc = fmaf(a.y, b.y, acc);
    acc = fmaf(a.z, b.z, acc);
    return fmaf(a.w, b.w, acc);
}

__device__ __forceinline__ short8 pack_bf8(float4 x0, float4 x1) {
    short8 s;
    s[0] = (short)f2bf(x0.x); s[1] = (short)f2bf(x0.y);
    s[2] = (short)f2bf(x0.z); s[3] = (short)f2bf(x0.w);
    s[4] = (short)f2bf(x1.x); s[5] = (short)f2bf(x1.y);
    s[6] = (short)f2bf(x1.z); s[7] = (short)f2bf(x1.w);
    return s;
}

// ---------------- embed: raw dots + per-block n2 partials (no atomics) -------
// grid (8 d-tiles, 32 b-pairs)
__global__ __launch_bounds__(256) void embed_kernel(
    const float* __restrict__ fs, const float* __restrict__ ft,
    const float* __restrict__ Ws, const float* __restrict__ bs,
    const float* __restrict__ Wt, const float* __restrict__ bt,
    float* __restrict__ vraw_s, float* __restrict__ vraw_t,
    float* __restrict__ n2part_s, float* __restrict__ n2part_t)
{
    __shared__ __align__(16) float4 FS[512];    // 2 b x 1024 f
    __shared__ __align__(16) float4 FT[1024];   // 2 b x 2048 f
    __shared__ float rS[4][2], rT[4][2];

    const int t  = threadIdx.x;
    const int dt = blockIdx.x;        // dims dt*16 .. dt*16+15
    const int b0 = blockIdx.y * 2;

    for (int q = t; q < 512; q += 256) {
        const int b = q >> 8, i = q & 255;
        FS[q] = ((const float4*)(fs + (size_t)(b0 + b) * 1024))[i];
    }
    for (int q = t; q < 1024; q += 256) {
        const int b = q >> 9, i = q & 511;
        FT[q] = ((const float4*)(ft + (size_t)(b0 + b) * 2048))[i];
    }
    __syncthreads();

    const int w = t >> 6, lane = t & 63;
    float ps0 = 0.0f, ps1 = 0.0f, pt0 = 0.0f, pt1 = 0.0f;

    #pragma unroll
    for (int r = 0; r < 4; ++r) {                 // s-side: 4 dims per wave
        const int d = dt * 16 + w * 4 + r;
        const float4* wrow = (const float4*)(Ws + (size_t)d * 1024);
        float a0 = 0.0f, a1 = 0.0f;
        #pragma unroll
        for (int i = 0; i < 4; ++i) {
            const float4 wv = wrow[i * 64 + lane];
            a0 = dot4(wv, FS[i * 64 + lane], a0);
            a1 = dot4(wv, FS[256 + i * 64 + lane], a1);
        }
        a0 = wave_reduce64(a0) + bs[d];
        a1 = wave_reduce64(a1) + bs[d];
        ps0 = fmaf(a0, a0, ps0);
        ps1 = fmaf(a1, a1, ps1);
        if (lane == 0) {
            vraw_s[(size_t)b0 * 128 + d]       = a0;
            vraw_s[(size_t)(b0 + 1) * 128 + d] = a1;
        }
    }
    #pragma unroll
    for (int r = 0; r < 4; ++r) {                 // t-side
        const int d = dt * 16 + w * 4 + r;
        const float4* wrow = (const float4*)(Wt + (size_t)d * 2048);
        float a0 = 0.0f, a1 = 0.0f;
        #pragma unroll
        for (int i = 0; i < 8; ++i) {
            const float4 wv = wrow[i * 64 + lane];
            a0 = dot4(wv, FT[i * 64 + lane], a0);
            a1 = dot4(wv, FT[512 + i * 64 + lane], a1);
        }
        a0 = wave_reduce64(a0) + bt[d];
        a1 = wave_reduce64(a1) + bt[d];
        pt0 = fmaf(a0, a0, pt0);
        pt1 = fmaf(a1, a1, pt1);
        if (lane == 0) {
            vraw_t[(size_t)b0 * 128 + d]       = a0;
            vraw_t[(size_t)(b0 + 1) * 128 + d] = a1;
        }
    }
    if (lane == 0) {
        rS[w][0] = ps0; rS[w][1] = ps1;
        rT[w][0] = pt0; rT[w][1] = pt1;
    }
    __syncthreads();
    if (t == 0) {
        n2part_s[dt * 64 + b0]     = rS[0][0] + rS[1][0] + rS[2][0] + rS[3][0];
        n2part_s[dt * 64 + b0 + 1] = rS[0][1] + rS[1][1] + rS[2][1] + rS[3][1];
        n2part_t[dt * 64 + b0]     = rT[0][0] + rT[1][0] + rT[2][0] + rT[3][0];
        n2part_t[dt * 64 + b0 + 1] = rT[0][1] + rT[1][1] + rT[2][1] + rT[3][1];
    }
}

// ---------------- zero-LDS, zero-barrier MFMA GEMM -> S[b][row] bf16 ---------
// B-frags (v, 64x128) register-resident per wave; A-frags (16 bank rows per
// chunk) straight from global; 16 MFMA per chunk; grid-stride, no syncs.
__global__ __launch_bounds__(256) void sgemm_kernel(
    const float* __restrict__ m1, const float* __restrict__ m2,
    const float* __restrict__ vraw_s, const float* __restrict__ vraw_t,
    const float* __restrict__ n2part_s, const float* __restrict__ n2part_t,
    float* __restrict__ n2s, float* __restrict__ n2t,
    float* __restrict__ acc, int* __restrict__ counter,
    unsigned short* __restrict__ S1, unsigned short* __restrict__ S2)
{
    const int bank = blockIdx.y;
    const float* __restrict__ bankp = bank ? m2 : m1;
    const float* __restrict__ vp    = bank ? vraw_s : vraw_t;   // m1 x v_t, m2 x v_s
    unsigned short* __restrict__ Sp = bank ? S2 : S1;

    // housekeeping: block 0 of each bank sums n2 partials, zeroes acc/counter
    if (blockIdx.x == 0) {
        if (threadIdx.x < 64) {
            const int b = threadIdx.x;
            const float* np = bank ? n2part_s : n2part_t;
            float s = 0.0f;
            #pragma unroll
            for (int p = 0; p < 8; ++p) s += np[p * 64 + b];
            (bank ? n2s : n2t)[b] = s;
            if (b < 2) acc[bank * 2 + b] = 0.0f;
        } else if (threadIdx.x == 64 && bank == 0) {
            counter[0] = 0;
        }
    }

    const int lane = threadIdx.x & 63;
    const int m  = lane & 15;          // A row within chunk / D col = v index n0+m
    const int q4 = lane >> 4;          // k-offset q4*8 ; D rows q4*4+r

    short8 vf[4][4];                   // B-operand fragments, register-resident
    #pragma unroll
    for (int n0i = 0; n0i < 4; ++n0i) {
        const float* vb = vp + (size_t)(n0i * 16 + m) * 128 + q4 * 8;
        #pragma unroll
        for (int kk = 0; kk < 4; ++kk)
            vf[n0i][kk] = pack_bf8(*(const float4*)(vb + kk * 32),
                                   *(const float4*)(vb + kk * 32 + 4));
    }

    const int w0 = blockIdx.x * 4 + (threadIdx.x >> 6);
    for (int c = w0; c < NCHUNK; c += GX * 4) {
        const float* ap = bankp + ((size_t)c * 16 + m) * 128 + q4 * 8;
        float4 a0[4], a1[4];
        #pragma unroll
        for (int kk = 0; kk < 4; ++kk) {
            a0[kk] = *(const float4*)(ap + kk * 32);
            a1[kk] = *(const float4*)(ap + kk * 32 + 4);
        }
        short8 af[4];
        #pragma unroll
        for (int kk = 0; kk < 4; ++kk) af[kk] = pack_bf8(a0[kk], a1[kk]);

        #pragma unroll
        for (int n0i = 0; n0i < 4; ++n0i) {
            f32x4 a4 = {0.f, 0.f, 0.f, 0.f};
            #pragma unroll
            for (int kk = 0; kk < 4; ++kk)
                a4 = __builtin_amdgcn_mfma_f32_16x16x32_bf16(af[kk], vf[n0i][kk], a4, 0, 0, 0);
            uint2 pk;
            pk.x = (unsigned)f2bf(a4[0]) | ((unsigned)f2bf(a4[1]) << 16);
            pk.y = (unsigned)f2bf(a4[2]) | ((unsigned)f2bf(a4[3]) << 16);
            *(uint2*)(Sp + (size_t)(n0i * 16 + m) * NDATA + c * 16 + q4 * 4) = pk;
        }
    }
}

// ---------------- gather negatives + fused final in last block ---------------
// grid (64 b, 8 parts): k = part*2048 + j*256 + t + 1 covers k=1..16384.
__global__ __launch_bounds__(256) void gather_kernel(
    const int* __restrict__ idx, const int* __restrict__ cidx,
    const unsigned short* __restrict__ S1, const unsigned short* __restrict__ S2,
    const float* __restrict__ n2t, const float* __restrict__ n2s,
    float* __restrict__ acc, int* __restrict__ counter,
    float* __restrict__ out)
{
    const int b = blockIdx.x, part = blockIdx.y, t = threadIdx.x;
    const float sct = INV_T * rsqrtf(n2t[b]);
    const float scs = INV_T * rsqrtf(n2s[b]);
    const unsigned short* __restrict__ S1b = S1 + (size_t)b * NDATA;
    const unsigned short* __restrict__ S2b = S2 + (size_t)b * NDATA;
    const int kbase = part * 2048 + 1;

    int rows[8];
    #pragma unroll
    for (int j = 0; j < 8; ++j)
        rows[j] = cidx[(size_t)b * KP1 + kbase + j * 256 + t];

    float v1[8], v2[8];
    #pragma unroll
    for (int j = 0; j < 8; ++j) {
        v1[j] = bf2f(S1b[rows[j]]);
        v2[j] = bf2f(S2b[rows[j]]);
    }

    float seT = 0.f, se2T = 0.f, seS = 0.f, se2S = 0.f;
    #pragma unroll
    for (int j = 0; j < 8; ++j) {
        const float e1 = __expf(v1[j] * sct);
        const float e2 = __expf(v2[j] * scs);
        seT += e1; se2T = fmaf(e1, e1, se2T);
        seS += e2; se2S = fmaf(e2, e2, se2S);
    }

    seT = wave_reduce64(seT);  se2T = wave_reduce64(se2T);
    seS = wave_reduce64(seS);  se2S = wave_reduce64(se2S);

    __shared__ float red[4][4];
    __shared__ int lastFlag;
    if ((t & 63) == 0) {
        const int w = t >> 6;
        red[w][0] = seT; red[w][1] = se2T; red[w][2] = seS; red[w][3] = se2S;
    }
    __syncthreads();
    if (t < 4) {
        atomicAdd(&acc[t], red[0][t] + red[1][t] + red[2][t] + red[3][t]);
        __threadfence();
    }
    __syncthreads();
    if (t == 0) lastFlag = (atomicAdd(counter, 1) == 64 * 8 - 1);
    __syncthreads();
    if (!lastFlag) return;

    // ---- final (last arriving block only) ----
    __shared__ float av[4];
    if (t < 4) av[t] = atomicAdd(&acc[t], 0.0f);   // coherent read
    __syncthreads();
    if (t >= 64) return;

    const int bb = t;                              // one wave, 64 lanes
    const int row = idx[bb];
    const float e1p = __expf(bf2f(S1[(size_t)bb * NDATA + row]) * INV_T * rsqrtf(n2t[bb]));
    const float e2p = __expf(bf2f(S2[(size_t)bb * NDATA + row]) * INV_T * rsqrtf(n2s[bb]));
    const float pseT = wave_reduce64(e1p);
    const float pseS = wave_reduce64(e2p);

    const float seT_neg = av[0], se2T_neg = av[1];
    const float seS_neg = av[2], se2S_neg = av[3];

    const float zn = (float)PTOT / (float)NDATA;
    const float invZt = zn / (seT_neg + pseT);
    const float invZs = zn / (seS_neg + pseS);

    const float c  = 0.16384f + 1e-7f;
    const float ic = 1.0f / c;
    const float PB = (float)(PTOT - BSZ);          // 1,048,576
    const float LOG_MPN_C = -6.1035156e-7f;        // ln(mPn / (mPn + 1e-7))

    const float negT = PB * LOG_MPN_C
                     - seT_neg * invZt * ic
                     + 0.5f * se2T_neg * invZt * invZt * ic * ic;
    const float negS = PB * LOG_MPN_C
                     - seS_neg * invZs * ic
                     + 0.5f * se2S_neg * invZs * invZs * ic * ic;

    const float x0t = e1p * invZt, x0s = e2p * invZs;
    float pos = __logf(x0t / (x0t + c)) + __logf(x0s / (x0s + c));
    pos = wave_reduce64(pos);

    if (bb == 0) out[0] = -(negT + negS + pos) * (1.0f / 64.0f);
}

extern "C" void kernel_launch(void* const* d_in, const int* in_sizes, int n_in,
                              void* d_out, int out_size, void* d_ws, size_t ws_size,
                              hipStream_t stream) {
    const float* fs   = (const float*)d_in[0];
    const float* ft   = (const float*)d_in[1];
    const int*   idx  = (const int*)d_in[2];
    const int*   cidx = (const int*)d_in[3];
    const float* Ws   = (const float*)d_in[4];
    const float* bs   = (const float*)d_in[5];
    const float* Wt   = (const float*)d_in[6];
    const float* bt   = (const float*)d_in[7];
    const float* m1   = (const float*)d_in[8];
    const float* m2   = (const float*)d_in[9];
    float* out = (float*)d_out;

    float* ws       = (float*)d_ws;
    float* n2t      = ws;                     // 64
    float* n2s      = ws + 64;                // 64
    float* acc      = ws + 128;               // 4
    int*   counter  = (int*)(ws + 132);       // 1 (+3 pad)
    float* n2part_s = ws + 136;               // 512
    float* n2part_t = ws + 648;               // 512
    float* vraw_s   = ws + 1160;              // 8192
    float* vraw_t   = vraw_s + 8192;          // 8192
    unsigned short* S1 = (unsigned short*)(vraw_t + 8192);  // 64 x NDATA bf16
    unsigned short* S2 = S1 + (size_t)BSZ * NDATA;

    embed_kernel<<<dim3(8, 32), dim3(256), 0, stream>>>(
        fs, ft, Ws, bs, Wt, bt, vraw_s, vraw_t, n2part_s, n2part_t);
    sgemm_kernel<<<dim3(GX, 2), dim3(256), 0, stream>>>(
        m1, m2, vraw_s, vraw_t, n2part_s, n2part_t,
        n2s, n2t, acc, counter, S1, S2);
    gather_kernel<<<dim3(64, 8), dim3(256), 0, stream>>>(
        idx, cidx, S1, S2, n2t, n2s, acc, counter, out);
}